// Round 1
// baseline (5766.949 us; speedup 1.0000x reference)
//
#include <hip/hip_runtime.h>

// Problem constants (match reference)
constexpr int NN   = 50000;          // nodes
constexpr int NE   = 800000;         // edges before self loops
constexpr int TOTE = NE + NN;        // edges incl self loops
constexpr int NHD  = 4;              // heads
constexpr int CC   = 32;             // channels per head
constexpr int HCC  = 128;            // NHD*CC
constexpr int NL   = 3;              // layers
constexpr int NG   = 128;            // graphs
constexpr int NOUT = 10;             // out channels
constexpr float BN_EPS = 1e-5f;

// ---------------------------------------------------------------- embed gather
__global__ __launch_bounds__(256) void k_embed(const int* __restrict__ idx,
                                               const float* __restrict__ embed,
                                               float* __restrict__ x) {
    int i = blockIdx.x * 256 + threadIdx.x;
    if (i >= NN * HCC) return;
    int n = i >> 7, c = i & 127;
    x[i] = embed[idx[n] * HCC + c];
}

// ------------------------------------------------------------------- BN stats
// grid-stride with stride multiple of 128 -> each thread owns one channel
__global__ __launch_bounds__(256) void k_bnstats(const float* __restrict__ x,
                                                 float* __restrict__ stats) {
    int i0 = blockIdx.x * 256 + threadIdx.x;
    int stride = gridDim.x * 256;                 // multiple of 128
    float s = 0.f, q = 0.f;
    for (int i = i0; i < NN * HCC; i += stride) {
        float v = x[i];
        s += v; q += v * v;
    }
    __shared__ float ssum[256], ssq[256];
    ssum[threadIdx.x] = s; ssq[threadIdx.x] = q;
    __syncthreads();
    if (threadIdx.x < HCC) {
        // channel of thread t is t&127 == t here
        atomicAdd(&stats[threadIdx.x],       ssum[threadIdx.x] + ssum[threadIdx.x + HCC]);
        atomicAdd(&stats[HCC + threadIdx.x], ssq[threadIdx.x]  + ssq[threadIdx.x + HCC]);
    }
}

__global__ void k_bnfin(const float* __restrict__ stats,
                        const float* __restrict__ gamma,
                        const float* __restrict__ beta,
                        float* __restrict__ ss) {
    int c = threadIdx.x;                          // 128 threads
    float mean = stats[c] * (1.0f / NN);
    float var  = stats[HCC + c] * (1.0f / NN) - mean * mean;
    float sc   = gamma[c] * rsqrtf(var + BN_EPS);
    ss[c]       = sc;
    ss[HCC + c] = beta[c] - mean * sc;
}

// ------------------------------------------- BN-apply + Linear(128->32) + ReLU
__global__ __launch_bounds__(256) void k_lin(const float* __restrict__ x,
                                             const float* __restrict__ ss,
                                             const float* __restrict__ W,  // [32,128]
                                             const float* __restrict__ b,  // [32]
                                             float* __restrict__ y) {      // [N,32]
    int i = blockIdx.x * 256 + threadIdx.x;
    if (i >= NN * CC) return;
    int n = i >> 5, j = i & 31;
    const float* xr = x + (size_t)n * HCC;
    const float* wr = W + j * HCC;
    float acc = b[j];
#pragma unroll
    for (int c = 0; c < HCC; c += 4) {
        float4 xv = *(const float4*)(xr + c);
        float4 wv = *(const float4*)(wr + c);
        float4 sc = *(const float4*)(ss + c);
        float4 sh = *(const float4*)(ss + HCC + c);
        acc += (xv.x * sc.x + sh.x) * wv.x;
        acc += (xv.y * sc.y + sh.y) * wv.y;
        acc += (xv.z * sc.z + sh.z) * wv.z;
        acc += (xv.w * sc.w + sh.w) * wv.w;
    }
    y[i] = fmaxf(acc, 0.f);
}

// -------------------------------------------------- GAT weight: y[N,32]->h[N,128]
__global__ __launch_bounds__(256) void k_gat(const float* __restrict__ y,
                                             const float* __restrict__ W,  // [128,32]
                                             float* __restrict__ h) {      // [N,128]
    int i = blockIdx.x * 256 + threadIdx.x;
    if (i >= NN * HCC) return;
    int n = i >> 7, k = i & 127;
    const float* yr = y + (size_t)n * CC;
    const float* wr = W + k * CC;
    float acc = 0.f;
#pragma unroll
    for (int j = 0; j < CC; j += 4) {
        float4 yv = *(const float4*)(yr + j);
        float4 wv = *(const float4*)(wr + j);
        acc += yv.x * wv.x + yv.y * wv.y + yv.z * wv.z + yv.w * wv.w;
    }
    h[i] = acc;
}

// -------------------------------------------------------- attention coefficients
__global__ __launch_bounds__(256) void k_att(const float* __restrict__ h,
                                             const float* __restrict__ aS, // [4,32]
                                             const float* __restrict__ aD,
                                             float* __restrict__ asrc,     // [N,4]
                                             float* __restrict__ adst) {
    int i = blockIdx.x * 256 + threadIdx.x;
    if (i >= NN * NHD) return;
    int n = i >> 2, hd = i & 3;
    const float* hr = h + (size_t)n * HCC + hd * CC;
    float s = 0.f, d = 0.f;
#pragma unroll
    for (int c = 0; c < CC; c += 4) {
        float4 hv = *(const float4*)(hr + c);
        float4 sv = *(const float4*)(aS + hd * CC + c);
        float4 dv = *(const float4*)(aD + hd * CC + c);
        s += hv.x * sv.x + hv.y * sv.y + hv.z * sv.z + hv.w * sv.w;
        d += hv.x * dv.x + hv.y * dv.y + hv.z * dv.z + hv.w * dv.w;
    }
    asrc[i] = s; adst[i] = d;
}

// ------------------------------------------------------------ init x_out = bias
__global__ __launch_bounds__(256) void k_initx(const float* __restrict__ gat_b,
                                               float* __restrict__ xo) {
    int i = blockIdx.x * 256 + threadIdx.x;
    if (i >= NN * HCC) return;
    xo[i] = gat_b[i & 127];
}

// -------------------------------------------------------- softmax denominators
__global__ __launch_bounds__(256) void k_denom(const int* __restrict__ ei,
                                               const float* __restrict__ asrc,
                                               const float* __restrict__ adst,
                                               float* __restrict__ z) {   // [N,4]
    int e = blockIdx.x * 256 + threadIdx.x;
    if (e >= TOTE) return;
    int s, d;
    if (e < NE) { s = ei[e]; d = ei[NE + e]; } else { s = d = e - NE; }
    float4 as = *(const float4*)(asrc + s * 4);
    float4 ad = *(const float4*)(adst + d * 4);
    float l0 = as.x + ad.x; l0 = l0 > 0.f ? l0 : 0.2f * l0;
    float l1 = as.y + ad.y; l1 = l1 > 0.f ? l1 : 0.2f * l1;
    float l2 = as.z + ad.z; l2 = l2 > 0.f ? l2 : 0.2f * l2;
    float l3 = as.w + ad.w; l3 = l3 > 0.f ? l3 : 0.2f * l3;
    atomicAdd(&z[d * 4 + 0], expf(l0));
    atomicAdd(&z[d * 4 + 1], expf(l1));
    atomicAdd(&z[d * 4 + 2], expf(l2));
    atomicAdd(&z[d * 4 + 3], expf(l3));
}

// -------------------------------------------------- message pass (32 thr/edge)
__global__ __launch_bounds__(256) void k_msg(const int* __restrict__ ei,
                                             const float* __restrict__ asrc,
                                             const float* __restrict__ adst,
                                             const float* __restrict__ z,
                                             const float* __restrict__ h,
                                             float* __restrict__ xo) {
    int i = blockIdx.x * 256 + threadIdx.x;
    if (i >= TOTE * 32) return;
    int e = i >> 5;
    int lane = i & 31;
    int s, d;
    if (e < NE) { s = ei[e]; d = ei[NE + e]; } else { s = d = e - NE; }
    int hd = lane >> 3;
    float logit = asrc[s * 4 + hd] + adst[d * 4 + hd];
    logit = logit > 0.f ? logit : 0.2f * logit;
    float alpha = expf(logit) / (z[d * 4 + hd] + 1e-16f);
    float4 hv = *(const float4*)(h + (size_t)s * HCC + lane * 4);
    float* o = xo + (size_t)d * HCC + lane * 4;
    atomicAdd(o + 0, hv.x * alpha);
    atomicAdd(o + 1, hv.y * alpha);
    atomicAdd(o + 2, hv.z * alpha);
    atomicAdd(o + 3, hv.w * alpha);
}

// ------------------------------------------------------- readout + graph pool
__global__ __launch_bounds__(256) void k_readout(const float* __restrict__ x,
                                                 const int* __restrict__ batch,
                                                 const float* __restrict__ W,  // [10,128]
                                                 const float* __restrict__ bb, // [10]
                                                 float* __restrict__ out) {    // [128,10]
    int i = blockIdx.x * 256 + threadIdx.x;
    if (i >= NN * NOUT) return;
    int n = i / NOUT, j = i - n * NOUT;
    const float* xr = x + (size_t)n * HCC;
    const float* wr = W + j * HCC;
    float acc = bb[j];
#pragma unroll
    for (int c = 0; c < HCC; c += 4) {
        float4 xv = *(const float4*)(xr + c);
        float4 wv = *(const float4*)(wr + c);
        acc += xv.x * wv.x + xv.y * wv.y + xv.z * wv.z + xv.w * wv.w;
    }
    atomicAdd(&out[batch[n] * NOUT + j], acc);
}

extern "C" void kernel_launch(void* const* d_in, const int* in_sizes, int n_in,
                              void* d_out, int out_size, void* d_ws, size_t ws_size,
                              hipStream_t stream) {
    const int*   x_idx = (const int*)d_in[0];
    const int*   ei    = (const int*)d_in[1];
    const int*   batch = (const int*)d_in[2];
    const float* embed = (const float*)d_in[3];
    const float* bn_g  = (const float*)d_in[4];
    const float* bn_b  = (const float*)d_in[5];
    const float* lin_W = (const float*)d_in[6];
    const float* lin_b = (const float*)d_in[7];
    const float* gat_W = (const float*)d_in[8];
    const float* att_s = (const float*)d_in[9];
    const float* att_d = (const float*)d_in[10];
    const float* gat_b = (const float*)d_in[11];
    const float* ro_W  = (const float*)d_in[12];
    const float* ro_b  = (const float*)d_in[13];
    float* out = (float*)d_out;

    // workspace layout (floats)
    float* x     = (float*)d_ws;                    // [N,128]  (doubles as x_out)
    float* h     = x + (size_t)NN * HCC;            // [N,128]
    float* y     = h + (size_t)NN * HCC;            // [N,32]
    float* asrc  = y + (size_t)NN * CC;             // [N,4]
    float* adst  = asrc + (size_t)NN * NHD;         // [N,4]
    float* z     = adst + (size_t)NN * NHD;         // [N,4]
    float* stats = z + (size_t)NN * NHD;            // [256] sum,sumsq
    float* ss    = stats + 2 * HCC;                 // [256] scale,shift

    k_embed<<<(NN * HCC + 255) / 256, 256, 0, stream>>>(x_idx, embed, x);

    for (int l = 0; l < NL; ++l) {
        hipMemsetAsync(stats, 0, 2 * HCC * sizeof(float), stream);
        hipMemsetAsync(z, 0, (size_t)NN * NHD * sizeof(float), stream);
        k_bnstats<<<512, 256, 0, stream>>>(x, stats);
        k_bnfin<<<1, HCC, 0, stream>>>(stats, bn_g + l * HCC, bn_b + l * HCC, ss);
        k_lin<<<(NN * CC + 255) / 256, 256, 0, stream>>>(x, ss, lin_W + l * CC * HCC,
                                                         lin_b + l * CC, y);
        k_gat<<<(NN * HCC + 255) / 256, 256, 0, stream>>>(y, gat_W + l * HCC * CC, h);
        k_att<<<(NN * NHD + 255) / 256, 256, 0, stream>>>(h, att_s + l * NHD * CC,
                                                          att_d + l * NHD * CC, asrc, adst);
        k_denom<<<(TOTE + 255) / 256, 256, 0, stream>>>(ei, asrc, adst, z);
        k_initx<<<(NN * HCC + 255) / 256, 256, 0, stream>>>(gat_b + l * HCC, x);
        k_msg<<<(TOTE * 32 + 255) / 256, 256, 0, stream>>>(ei, asrc, adst, z, h, x);
    }

    hipMemsetAsync(out, 0, NG * NOUT * sizeof(float), stream);
    k_readout<<<(NN * NOUT + 255) / 256, 256, 0, stream>>>(x, batch, ro_W, ro_b, out);
}

// Round 2
// 1424.494 us; speedup vs baseline: 4.0484x; 4.0484x over previous
//
#include <hip/hip_runtime.h>

// Problem constants (match reference)
constexpr int NN   = 50000;          // nodes
constexpr int NE   = 800000;         // edges before self loops
constexpr int NHD  = 4;              // heads
constexpr int CC   = 32;             // channels per head
constexpr int HCC  = 128;            // NHD*CC
constexpr int NL   = 3;              // layers
constexpr int NG   = 128;            // graphs
constexpr int NOUT = 10;             // out channels
constexpr float BN_EPS = 1e-5f;

// ---------------------------------------------------------------- embed gather
__global__ __launch_bounds__(256) void k_embed(const int* __restrict__ idx,
                                               const float* __restrict__ embed,
                                               float* __restrict__ x) {
    int i = blockIdx.x * 256 + threadIdx.x;
    if (i >= NN * HCC) return;
    int n = i >> 7, c = i & 127;
    x[i] = embed[idx[n] * HCC + c];
}

// ------------------------------------------------------------ CSR build: degree
__global__ __launch_bounds__(256) void k_hist(const int* __restrict__ ei,
                                              int* __restrict__ deg) {
    int e = blockIdx.x * 256 + threadIdx.x;
    if (e >= NE) return;
    atomicAdd(&deg[ei[NE + e]], 1);
}

// single-block exclusive scan of deg[0..NN) -> rowptr
__global__ __launch_bounds__(1024) void k_scan(const int* __restrict__ deg,
                                               int* __restrict__ rowptr) {
    __shared__ int buf[1024];
    __shared__ int carry;
    if (threadIdx.x == 0) carry = 0;
    __syncthreads();
    for (int base = 0; base < NN; base += 1024) {
        int i = base + threadIdx.x;
        int v = (i < NN) ? deg[i] : 0;
        buf[threadIdx.x] = v;
        __syncthreads();
#pragma unroll
        for (int off = 1; off < 1024; off <<= 1) {
            int t = (threadIdx.x >= off) ? buf[threadIdx.x - off] : 0;
            __syncthreads();
            buf[threadIdx.x] += t;
            __syncthreads();
        }
        if (i < NN) rowptr[i] = carry + buf[threadIdx.x] - v;   // exclusive
        __syncthreads();
        if (threadIdx.x == 0) carry += buf[1023];
        __syncthreads();
    }
}

// scatter edges by dst. Mutates rowptr: afterwards rowptr[d] == end(d).
__global__ __launch_bounds__(256) void k_scatter(const int* __restrict__ ei,
                                                 int* __restrict__ rowptr,
                                                 int* __restrict__ e_src) {
    int e = blockIdx.x * 256 + threadIdx.x;
    if (e >= NE) return;
    int d = ei[NE + e];
    int pos = atomicAdd(&rowptr[d], 1);
    e_src[pos] = ei[e];
}

// ------------------------------------------------------------------- BN stats
__global__ __launch_bounds__(256) void k_bnstats(const float* __restrict__ x,
                                                 float* __restrict__ stats) {
    int i0 = blockIdx.x * 256 + threadIdx.x;
    int stride = gridDim.x * 256;                 // multiple of 128
    float s = 0.f, q = 0.f;
    for (int i = i0; i < NN * HCC; i += stride) {
        float v = x[i];
        s += v; q += v * v;
    }
    __shared__ float ssum[256], ssq[256];
    ssum[threadIdx.x] = s; ssq[threadIdx.x] = q;
    __syncthreads();
    if (threadIdx.x < HCC) {
        atomicAdd(&stats[threadIdx.x],       ssum[threadIdx.x] + ssum[threadIdx.x + HCC]);
        atomicAdd(&stats[HCC + threadIdx.x], ssq[threadIdx.x]  + ssq[threadIdx.x + HCC]);
    }
}

__global__ void k_bnfin(const float* __restrict__ stats,
                        const float* __restrict__ gamma,
                        const float* __restrict__ beta,
                        float* __restrict__ ss) {
    int c = threadIdx.x;                          // 128 threads
    float mean = stats[c] * (1.0f / NN);
    float var  = stats[HCC + c] * (1.0f / NN) - mean * mean;
    float sc   = gamma[c] * rsqrtf(var + BN_EPS);
    ss[c]       = sc;
    ss[HCC + c] = beta[c] - mean * sc;
}

// ------------------------------------------- BN-apply + Linear(128->32) + ReLU
__global__ __launch_bounds__(256) void k_lin(const float* __restrict__ x,
                                             const float* __restrict__ ss,
                                             const float* __restrict__ W,  // [32,128]
                                             const float* __restrict__ b,  // [32]
                                             float* __restrict__ y) {      // [N,32]
    int i = blockIdx.x * 256 + threadIdx.x;
    if (i >= NN * CC) return;
    int n = i >> 5, j = i & 31;
    const float* xr = x + (size_t)n * HCC;
    const float* wr = W + j * HCC;
    float acc = b[j];
#pragma unroll
    for (int c = 0; c < HCC; c += 4) {
        float4 xv = *(const float4*)(xr + c);
        float4 wv = *(const float4*)(wr + c);
        float4 sc = *(const float4*)(ss + c);
        float4 sh = *(const float4*)(ss + HCC + c);
        acc += (xv.x * sc.x + sh.x) * wv.x;
        acc += (xv.y * sc.y + sh.y) * wv.y;
        acc += (xv.z * sc.z + sh.z) * wv.z;
        acc += (xv.w * sc.w + sh.w) * wv.w;
    }
    y[i] = fmaxf(acc, 0.f);
}

// -------------------------------------------------- GAT weight: y[N,32]->h[N,128]
__global__ __launch_bounds__(256) void k_gat(const float* __restrict__ y,
                                             const float* __restrict__ W,  // [128,32]
                                             float* __restrict__ h) {      // [N,128]
    int i = blockIdx.x * 256 + threadIdx.x;
    if (i >= NN * HCC) return;
    int n = i >> 7, k = i & 127;
    const float* yr = y + (size_t)n * CC;
    const float* wr = W + k * CC;
    float acc = 0.f;
#pragma unroll
    for (int j = 0; j < CC; j += 4) {
        float4 yv = *(const float4*)(yr + j);
        float4 wv = *(const float4*)(wr + j);
        acc += yv.x * wv.x + yv.y * wv.y + yv.z * wv.z + yv.w * wv.w;
    }
    h[i] = acc;
}

// -------------------------------------------------------- attention coefficients
__global__ __launch_bounds__(256) void k_att(const float* __restrict__ h,
                                             const float* __restrict__ aS, // [4,32]
                                             const float* __restrict__ aD,
                                             float* __restrict__ asrc,     // [N,4]
                                             float* __restrict__ adst) {
    int i = blockIdx.x * 256 + threadIdx.x;
    if (i >= NN * NHD) return;
    int n = i >> 2, hd = i & 3;
    const float* hr = h + (size_t)n * HCC + hd * CC;
    float s = 0.f, d = 0.f;
#pragma unroll
    for (int c = 0; c < CC; c += 4) {
        float4 hv = *(const float4*)(hr + c);
        float4 sv = *(const float4*)(aS + hd * CC + c);
        float4 dv = *(const float4*)(aD + hd * CC + c);
        s += hv.x * sv.x + hv.y * sv.y + hv.z * sv.z + hv.w * sv.w;
        d += hv.x * dv.x + hv.y * dv.y + hv.z * dv.z + hv.w * dv.w;
    }
    asrc[i] = s; adst[i] = d;
}

// -------------------- gather-aggregate: one wave per dst node, lane = 2 channels
// rowptr has been mutated by k_scatter: rowptr[d] == end(d), begin(d) == rowptr[d-1]
__global__ __launch_bounds__(256) void k_agg(const int* __restrict__ rowptr,
                                             const int* __restrict__ e_src,
                                             const float* __restrict__ asrc,
                                             const float* __restrict__ adst,
                                             const float* __restrict__ h,
                                             const float* __restrict__ gat_b,
                                             float* __restrict__ xo) {
    int d = blockIdx.x * 4 + (threadIdx.x >> 6);
    if (d >= NN) return;
    int lane = threadIdx.x & 63;
    int c0 = lane * 2;              // channels c0, c0+1 (same head)
    int hd = lane >> 4;
    float adstv = adst[d * 4 + hd];

    // self loop (reference appends self loops)
    float sl = asrc[d * 4 + hd] + adstv;
    sl = sl > 0.f ? sl : 0.2f * sl;
    float w = expf(sl);
    float2 hv = *(const float2*)(h + (size_t)d * HCC + c0);
    float acc0 = w * hv.x, acc1 = w * hv.y, wsum = w;

    int begin = (d == 0) ? 0 : rowptr[d - 1];
    int end   = rowptr[d];

    int j = begin;
    int sn = (j < end) ? e_src[j] : 0;
    float an = (j < end) ? asrc[sn * 4 + hd] : 0.f;
    while (j < end) {
        int s = sn; float a = an;
        int jn = j + 1;
        if (jn < end) { sn = e_src[jn]; an = asrc[sn * 4 + hd]; }
        float lg = a + adstv;
        lg = lg > 0.f ? lg : 0.2f * lg;
        float ww = expf(lg);
        float2 hh = *(const float2*)(h + (size_t)s * HCC + c0);
        acc0 += ww * hh.x;
        acc1 += ww * hh.y;
        wsum += ww;
        j = jn;
    }
    float inv = 1.0f / (wsum + 1e-16f);
    float2 o;
    o.x = acc0 * inv + gat_b[c0];
    o.y = acc1 * inv + gat_b[c0 + 1];
    *(float2*)(xo + (size_t)d * HCC + c0) = o;
}

// ------------------------------------------------------- readout + graph pool
__global__ __launch_bounds__(256) void k_readout(const float* __restrict__ x,
                                                 const int* __restrict__ batch,
                                                 const float* __restrict__ W,  // [10,128]
                                                 const float* __restrict__ bb, // [10]
                                                 float* __restrict__ out) {    // [128,10]
    int i = blockIdx.x * 256 + threadIdx.x;
    if (i >= NN * NOUT) return;
    int n = i / NOUT, j = i - n * NOUT;
    const float* xr = x + (size_t)n * HCC;
    const float* wr = W + j * HCC;
    float acc = bb[j];
#pragma unroll
    for (int c = 0; c < HCC; c += 4) {
        float4 xv = *(const float4*)(xr + c);
        float4 wv = *(const float4*)(wr + c);
        acc += xv.x * wv.x + xv.y * wv.y + xv.z * wv.z + xv.w * wv.w;
    }
    atomicAdd(&out[batch[n] * NOUT + j], acc);
}

extern "C" void kernel_launch(void* const* d_in, const int* in_sizes, int n_in,
                              void* d_out, int out_size, void* d_ws, size_t ws_size,
                              hipStream_t stream) {
    const int*   x_idx = (const int*)d_in[0];
    const int*   ei    = (const int*)d_in[1];
    const int*   batch = (const int*)d_in[2];
    const float* embed = (const float*)d_in[3];
    const float* bn_g  = (const float*)d_in[4];
    const float* bn_b  = (const float*)d_in[5];
    const float* lin_W = (const float*)d_in[6];
    const float* lin_b = (const float*)d_in[7];
    const float* gat_W = (const float*)d_in[8];
    const float* att_s = (const float*)d_in[9];
    const float* att_d = (const float*)d_in[10];
    const float* gat_b = (const float*)d_in[11];
    const float* ro_W  = (const float*)d_in[12];
    const float* ro_b  = (const float*)d_in[13];
    float* out = (float*)d_out;

    // workspace layout
    float* x     = (float*)d_ws;                    // [N,128] ping
    float* h     = x + (size_t)NN * HCC;            // [N,128]
    float* y     = h + (size_t)NN * HCC;            // [N,32]
    float* asrc  = y + (size_t)NN * CC;             // [N,4]
    float* adst  = asrc + (size_t)NN * NHD;         // [N,4]
    float* stats = adst + (size_t)NN * NHD;         // [256] sum,sumsq
    float* ss    = stats + 2 * HCC;                 // [256] scale,shift
    int*   deg    = (int*)(ss + 2 * HCC);           // [N]
    int*   rowptr = deg + NN;                       // [N]
    int*   e_src  = rowptr + NN;                    // [E]

    // CSR build (graph is static across layers)
    hipMemsetAsync(deg, 0, NN * sizeof(int), stream);
    k_embed<<<(NN * HCC + 255) / 256, 256, 0, stream>>>(x_idx, embed, x);
    k_hist<<<(NE + 255) / 256, 256, 0, stream>>>(ei, deg);
    k_scan<<<1, 1024, 0, stream>>>(deg, rowptr);
    k_scatter<<<(NE + 255) / 256, 256, 0, stream>>>(ei, rowptr, e_src);

    for (int l = 0; l < NL; ++l) {
        hipMemsetAsync(stats, 0, 2 * HCC * sizeof(float), stream);
        k_bnstats<<<512, 256, 0, stream>>>(x, stats);
        k_bnfin<<<1, HCC, 0, stream>>>(stats, bn_g + l * HCC, bn_b + l * HCC, ss);
        k_lin<<<(NN * CC + 255) / 256, 256, 0, stream>>>(x, ss, lin_W + l * CC * HCC,
                                                         lin_b + l * CC, y);
        k_gat<<<(NN * HCC + 255) / 256, 256, 0, stream>>>(y, gat_W + l * HCC * CC, h);
        k_att<<<(NN * NHD + 255) / 256, 256, 0, stream>>>(h, att_s + l * NHD * CC,
                                                          att_d + l * NHD * CC, asrc, adst);
        k_agg<<<(NN + 3) / 4, 256, 0, stream>>>(rowptr, e_src, asrc, adst, h,
                                                gat_b + l * HCC, x);
    }

    hipMemsetAsync(out, 0, NG * NOUT * sizeof(float), stream);
    k_readout<<<(NN * NOUT + 255) / 256, 256, 0, stream>>>(x, batch, ro_W, ro_b, out);
}

// Round 4
// 789.725 us; speedup vs baseline: 7.3025x; 1.8038x over previous
//
#include <hip/hip_runtime.h>

// Problem constants (match reference)
constexpr int NN   = 50000;          // nodes
constexpr int NE   = 800000;         // edges before self loops
constexpr int NHD  = 4;              // heads
constexpr int CC   = 32;             // channels per head
constexpr int HCC  = 128;            // NHD*CC
constexpr int NL   = 3;              // layers
constexpr int NG   = 128;            // graphs
constexpr int NOUT = 10;             // out channels
constexpr float BN_EPS = 1e-5f;

constexpr int XS = 133;              // LDS x-row stride: (5n+c)%32 -> 2-way (free)
constexpr int YS = 33;               // LDS y-row stride: conflict-free

// -------------------------------------- embed gather + BN stats for layer 0
__global__ __launch_bounds__(256) void k_embed_stats(const int* __restrict__ idx,
                                                     const float* __restrict__ embed,
                                                     float* __restrict__ x,
                                                     float* __restrict__ stats) {
    int i0 = blockIdx.x * 256 + threadIdx.x;
    int stride = gridDim.x * 256;                 // multiple of 128
    float s = 0.f, q = 0.f;
    for (int i = i0; i < NN * HCC; i += stride) {
        float v = embed[idx[i >> 7] * HCC + (i & 127)];
        x[i] = v; s += v; q += v * v;
    }
    __shared__ float ssum[256], ssq[256];
    ssum[threadIdx.x] = s; ssq[threadIdx.x] = q;
    __syncthreads();
    if (threadIdx.x < HCC) {
        atomicAdd(&stats[threadIdx.x],       ssum[threadIdx.x] + ssum[threadIdx.x + HCC]);
        atomicAdd(&stats[HCC + threadIdx.x], ssq[threadIdx.x]  + ssq[threadIdx.x + HCC]);
    }
}

// ------------------------------------------------------------ CSR build: degree
__global__ __launch_bounds__(256) void k_hist(const int* __restrict__ ei,
                                              int* __restrict__ deg) {
    int e = blockIdx.x * 256 + threadIdx.x;
    if (e >= NE) return;
    atomicAdd(&deg[ei[NE + e]], 1);
}

// chunked single-block exclusive scan: each thread serially scans 49 elements
__global__ __launch_bounds__(1024) void k_scan(const int* __restrict__ deg,
                                               int* __restrict__ rowptr) {
    __shared__ int sh[1024];
    int tid = threadIdx.x;
    const int CH = (NN + 1023) / 1024;            // 49
    int st = tid * CH, en = min(st + CH, NN);
    int sum = 0;
    for (int i = st; i < en; i++) sum += deg[i];
    sh[tid] = sum;
    __syncthreads();
    for (int off = 1; off < 1024; off <<= 1) {
        int v = (tid >= off) ? sh[tid - off] : 0;
        __syncthreads();
        sh[tid] += v;
        __syncthreads();
    }
    int base = sh[tid] - sum;                     // exclusive prefix of chunk
    for (int i = st; i < en; i++) { rowptr[i] = base; base += deg[i]; }
}

// scatter edges by dst. Mutates rowptr: afterwards rowptr[d] == end(d).
__global__ __launch_bounds__(256) void k_scatter(const int* __restrict__ ei,
                                                 int* __restrict__ rowptr,
                                                 int* __restrict__ e_src) {
    int e = blockIdx.x * 256 + threadIdx.x;
    if (e >= NE) return;
    int d = ei[NE + e];
    int pos = atomicAdd(&rowptr[d], 1);
    e_src[pos] = ei[e];
}

// ------------------------------------------------------- BN finalize (tiny)
__global__ void k_bnfin(const float* __restrict__ stats,
                        const float* __restrict__ gamma,
                        const float* __restrict__ beta,
                        float* __restrict__ ss) {
    int c = threadIdx.x;                          // 128 threads
    float mean = stats[c] * (1.0f / NN);
    float var  = stats[HCC + c] * (1.0f / NN) - mean * mean;
    float sc   = gamma[c] * rsqrtf(var + BN_EPS);
    ss[c]       = sc;
    ss[HCC + c] = beta[c] - mean * sc;
}

// ---------- fused BN-apply + Linear(128->32)+ReLU + GATweight(32->128) + att dots
// block = 256 threads = 4 waves, 64 nodes. Wave wv owns j-slice [wv*8,wv*8+8) in
// stage 1 and k-slice / head wv in stage 2 -> all weight LDS reads wave-uniform.
__global__ __launch_bounds__(256) void k_fused(const float* __restrict__ x,
                                               const float* __restrict__ ss,
                                               const float* __restrict__ W1, // [32,128]
                                               const float* __restrict__ b1, // [32]
                                               const float* __restrict__ W2, // [128,32]
                                               const float* __restrict__ aS, // [4,32]
                                               const float* __restrict__ aD, // [4,32]
                                               float* __restrict__ h,        // [N,128]
                                               float* __restrict__ asrc,     // [N,4]
                                               float* __restrict__ adst) {   // [N,4]
    __shared__ float xb[64 * XS];
    __shared__ float yt[64 * YS];
    __shared__ float w1[32 * 128];
    __shared__ float w2[128 * 32];
    __shared__ float attS[128], attD[128], ssl[256];
    int tid = threadIdx.x;
    int node0 = blockIdx.x * 64;
    int nNodes = min(64, NN - node0);

    for (int i = tid; i < 4096; i += 256) { w1[i] = W1[i]; w2[i] = W2[i]; }
    if (tid < 128) { attS[tid] = aS[tid]; attD[tid] = aD[tid]; }
    ssl[tid] = ss[tid];
    __syncthreads();   // ssl is read cross-wave by the staging loop below (R3 bug fix)

    // stage x tile with BN applied (coalesced float4 global reads)
    for (int f4 = tid; f4 < nNodes * 32; f4 += 256) {
        int f = f4 * 4; int n = f >> 7; int c = f & 127;
        float4 xv = *(const float4*)(x + (size_t)(node0 + n) * HCC + c);
        float* dst = &xb[n * XS + c];
        dst[0] = xv.x * ssl[c]     + ssl[HCC + c];
        dst[1] = xv.y * ssl[c + 1] + ssl[HCC + c + 1];
        dst[2] = xv.z * ssl[c + 2] + ssl[HCC + c + 2];
        dst[3] = xv.w * ssl[c + 3] + ssl[HCC + c + 3];
    }
    __syncthreads();

    int lane = tid & 63, wv = tid >> 6;
    int n = lane;

    // ---- stage 1: y[n][j0..j0+7]
    {
        int j0 = wv * 8;
        float acc[8];
#pragma unroll
        for (int k = 0; k < 8; k++) acc[k] = b1[j0 + k];
        if (n < nNodes) {
            for (int cb = 0; cb < 128; cb += 4) {
                float xv0 = xb[n * XS + cb],     xv1 = xb[n * XS + cb + 1];
                float xv2 = xb[n * XS + cb + 2], xv3 = xb[n * XS + cb + 3];
#pragma unroll
                for (int k = 0; k < 8; k++) {
                    float4 w = *(const float4*)&w1[(j0 + k) * 128 + cb];
                    acc[k] += xv0 * w.x + xv1 * w.y + xv2 * w.z + xv3 * w.w;
                }
            }
#pragma unroll
            for (int k = 0; k < 8; k++) yt[n * YS + j0 + k] = fmaxf(acc[k], 0.f);
        }
    }
    __syncthreads();

    // ---- stage 2: h[n][k0..k0+31], head hd = wv, + attention dots
    if (n < nNodes) {
        int k0 = wv * 32, hd = wv;
        float yreg[32];
#pragma unroll
        for (int j = 0; j < 32; j++) yreg[j] = yt[n * YS + j];
        float sa = 0.f, da = 0.f;
        float* hrow = h + (size_t)(node0 + n) * HCC + k0;
        for (int kb = 0; kb < 32; kb += 8) {
            float acck[8];
#pragma unroll
            for (int kk = 0; kk < 8; kk++) acck[kk] = 0.f;
#pragma unroll
            for (int j = 0; j < 32; j += 4) {
#pragma unroll
                for (int kk = 0; kk < 8; kk++) {
                    float4 w = *(const float4*)&w2[(k0 + kb + kk) * 32 + j];
                    acck[kk] += yreg[j] * w.x + yreg[j + 1] * w.y +
                                yreg[j + 2] * w.z + yreg[j + 3] * w.w;
                }
            }
#pragma unroll
            for (int kk = 0; kk < 8; kk++) {
                sa += acck[kk] * attS[hd * 32 + kb + kk];
                da += acck[kk] * attD[hd * 32 + kb + kk];
            }
            float4 o0 = make_float4(acck[0], acck[1], acck[2], acck[3]);
            float4 o1 = make_float4(acck[4], acck[5], acck[6], acck[7]);
            *(float4*)(hrow + kb)     = o0;
            *(float4*)(hrow + kb + 4) = o1;
        }
        asrc[(node0 + n) * 4 + hd] = sa;
        adst[(node0 + n) * 4 + hd] = da;
    }
}

// -------- gather-aggregate: wave per 8 nodes, lane = 2 channels; 4-edge unroll.
// Also accumulates BN stats of the produced x for the next layer.
__global__ __launch_bounds__(256) void k_agg(const int* __restrict__ rowptr,
                                             const int* __restrict__ e_src,
                                             const float* __restrict__ asrc,
                                             const float* __restrict__ adst,
                                             const float* __restrict__ h,
                                             const float* __restrict__ gat_b,
                                             float* __restrict__ xo,
                                             float* __restrict__ stats) {
    int tid = threadIdx.x, lane = tid & 63, wv = tid >> 6;
    int c0 = lane * 2, hd = lane >> 4;
    int nodeBase = blockIdx.x * 32 + wv * 8;
    float bs0 = gat_b[c0], bs1 = gat_b[c0 + 1];
    float S0 = 0, S1 = 0, Q0 = 0, Q1 = 0;
    for (int nn = 0; nn < 8; nn++) {
        int d = nodeBase + nn;
        if (d >= NN) break;
        float adv = adst[d * 4 + hd];
        float sl = asrc[d * 4 + hd] + adv; sl = sl > 0.f ? sl : 0.2f * sl;
        float w = __expf(sl);
        float2 hv = *(const float2*)(h + (size_t)d * HCC + c0);
        float a0 = w * hv.x, a1 = w * hv.y, ws = w;
        int begin = d ? rowptr[d - 1] : 0, end = rowptr[d];
        int j = begin;
        for (; j + 4 <= end; j += 4) {
            int sA = e_src[j], sB = e_src[j + 1], sC = e_src[j + 2], sD = e_src[j + 3];
            float lA = asrc[sA * 4 + hd] + adv;
            float lB = asrc[sB * 4 + hd] + adv;
            float lC = asrc[sC * 4 + hd] + adv;
            float lD = asrc[sD * 4 + hd] + adv;
            float2 hA = *(const float2*)(h + (size_t)sA * HCC + c0);
            float2 hB = *(const float2*)(h + (size_t)sB * HCC + c0);
            float2 hC = *(const float2*)(h + (size_t)sC * HCC + c0);
            float2 hD = *(const float2*)(h + (size_t)sD * HCC + c0);
            lA = lA > 0.f ? lA : 0.2f * lA;  lB = lB > 0.f ? lB : 0.2f * lB;
            lC = lC > 0.f ? lC : 0.2f * lC;  lD = lD > 0.f ? lD : 0.2f * lD;
            float wA = __expf(lA), wB = __expf(lB), wC = __expf(lC), wD = __expf(lD);
            a0 += wA * hA.x + wB * hB.x + wC * hC.x + wD * hD.x;
            a1 += wA * hA.y + wB * hB.y + wC * hC.y + wD * hD.y;
            ws += wA + wB + wC + wD;
        }
        for (; j < end; j++) {
            int s = e_src[j];
            float l = asrc[s * 4 + hd] + adv; l = l > 0.f ? l : 0.2f * l;
            float we = __expf(l);
            float2 hh = *(const float2*)(h + (size_t)s * HCC + c0);
            a0 += we * hh.x; a1 += we * hh.y; ws += we;
        }
        float inv = 1.0f / (ws + 1e-16f);
        float o0 = a0 * inv + bs0, o1 = a1 * inv + bs1;
        *(float2*)(xo + (size_t)d * HCC + c0) = make_float2(o0, o1);
        S0 += o0; S1 += o1; Q0 += o0 * o0; Q1 += o1 * o1;
    }
    __shared__ float redS[512], redQ[512];
    redS[wv * 128 + c0] = S0; redS[wv * 128 + c0 + 1] = S1;
    redQ[wv * 128 + c0] = Q0; redQ[wv * 128 + c0 + 1] = Q1;
    __syncthreads();
    if (tid < 128) {
        float v = redS[tid] + redS[128 + tid] + redS[256 + tid] + redS[384 + tid];
        atomicAdd(&stats[tid], v);
    } else if (tid < 256) {
        int c = tid - 128;
        float v = redQ[c] + redQ[128 + c] + redQ[256 + c] + redQ[384 + c];
        atomicAdd(&stats[128 + c], v);
    }
}

// ------------------------------------------------------- readout + graph pool
__global__ __launch_bounds__(256) void k_readout(const float* __restrict__ x,
                                                 const int* __restrict__ batch,
                                                 const float* __restrict__ W,  // [10,128]
                                                 const float* __restrict__ bb, // [10]
                                                 float* __restrict__ out) {    // [128,10]
    int i = blockIdx.x * 256 + threadIdx.x;
    if (i >= NN * NOUT) return;
    int n = i / NOUT, j = i - n * NOUT;
    const float* xr = x + (size_t)n * HCC;
    const float* wr = W + j * HCC;
    float acc = bb[j];
#pragma unroll
    for (int c = 0; c < HCC; c += 4) {
        float4 xv = *(const float4*)(xr + c);
        float4 wv = *(const float4*)(wr + c);
        acc += xv.x * wv.x + xv.y * wv.y + xv.z * wv.z + xv.w * wv.w;
    }
    atomicAdd(&out[batch[n] * NOUT + j], acc);
}

extern "C" void kernel_launch(void* const* d_in, const int* in_sizes, int n_in,
                              void* d_out, int out_size, void* d_ws, size_t ws_size,
                              hipStream_t stream) {
    const int*   x_idx = (const int*)d_in[0];
    const int*   ei    = (const int*)d_in[1];
    const int*   batch = (const int*)d_in[2];
    const float* embed = (const float*)d_in[3];
    const float* bn_g  = (const float*)d_in[4];
    const float* bn_b  = (const float*)d_in[5];
    const float* lin_W = (const float*)d_in[6];
    const float* lin_b = (const float*)d_in[7];
    const float* gat_W = (const float*)d_in[8];
    const float* att_s = (const float*)d_in[9];
    const float* att_d = (const float*)d_in[10];
    const float* gat_b = (const float*)d_in[11];
    const float* ro_W  = (const float*)d_in[12];
    const float* ro_b  = (const float*)d_in[13];
    float* out = (float*)d_out;

    // workspace layout
    float* x     = (float*)d_ws;                    // [N,128]
    float* h     = x + (size_t)NN * HCC;            // [N,128]
    float* asrc  = h + (size_t)NN * HCC;            // [N,4]
    float* adst  = asrc + (size_t)NN * NHD;         // [N,4]
    float* stats = adst + (size_t)NN * NHD;         // [256] sum,sumsq
    float* ss    = stats + 2 * HCC;                 // [256] scale,shift
    int*   deg    = (int*)(ss + 2 * HCC);           // [N]
    int*   rowptr = deg + NN;                       // [N]
    int*   e_src  = rowptr + NN;                    // [E]

    hipMemsetAsync(stats, 0, 2 * HCC * sizeof(float), stream);
    hipMemsetAsync(deg, 0, NN * sizeof(int), stream);

    k_embed_stats<<<512, 256, 0, stream>>>(x_idx, embed, x, stats);

    // CSR build (graph is static across layers)
    k_hist<<<(NE + 255) / 256, 256, 0, stream>>>(ei, deg);
    k_scan<<<1, 1024, 0, stream>>>(deg, rowptr);
    k_scatter<<<(NE + 255) / 256, 256, 0, stream>>>(ei, rowptr, e_src);

    for (int l = 0; l < NL; ++l) {
        k_bnfin<<<1, HCC, 0, stream>>>(stats, bn_g + l * HCC, bn_b + l * HCC, ss);
        k_fused<<<(NN + 63) / 64, 256, 0, stream>>>(x, ss,
                                                    lin_W + l * CC * HCC, lin_b + l * CC,
                                                    gat_W + l * HCC * CC,
                                                    att_s + l * NHD * CC,
                                                    att_d + l * NHD * CC,
                                                    h, asrc, adst);
        hipMemsetAsync(stats, 0, 2 * HCC * sizeof(float), stream);
        k_agg<<<(NN + 31) / 32, 256, 0, stream>>>(rowptr, e_src, asrc, adst, h,
                                                  gat_b + l * HCC, x, stats);
    }

    hipMemsetAsync(out, 0, NG * NOUT * sizeof(float), stream);
    k_readout<<<(NN * NOUT + 255) / 256, 256, 0, stream>>>(x, batch, ro_W, ro_b, out);
}

// Round 5
// 728.494 us; speedup vs baseline: 7.9163x; 1.0841x over previous
//
#include <hip/hip_runtime.h>

// Problem constants (match reference)
constexpr int NN   = 50000;          // nodes
constexpr int NE   = 800000;         // edges before self loops
constexpr int NHD  = 4;              // heads
constexpr int CC   = 32;             // channels per head
constexpr int HCC  = 128;            // NHD*CC
constexpr int NL   = 3;              // layers
constexpr int NG   = 128;            // graphs
constexpr int NOUT = 10;             // out channels
constexpr float BN_EPS = 1e-5f;

constexpr int XS = 133;              // LDS x-row stride
constexpr int YS = 33;               // LDS y-row stride

// fp32 -> bf16 (round-to-nearest-even), packed pair helpers
__device__ inline unsigned f2bf_pack(float a, float b) {
    unsigned ua = __float_as_uint(a); ua += 0x7FFFu + ((ua >> 16) & 1u);
    unsigned ub = __float_as_uint(b); ub += 0x7FFFu + ((ub >> 16) & 1u);
    return (ua >> 16) | (ub & 0xFFFF0000u);
}
__device__ inline float bf_lo(unsigned p) { return __uint_as_float(p << 16); }
__device__ inline float bf_hi(unsigned p) { return __uint_as_float(p & 0xFFFF0000u); }

// -------------------------------------- embed gather + BN stats for layer 0
__global__ __launch_bounds__(256) void k_embed_stats(const int* __restrict__ idx,
                                                     const float* __restrict__ embed,
                                                     float* __restrict__ x,
                                                     float* __restrict__ stats) {
    int i0 = blockIdx.x * 256 + threadIdx.x;
    int stride = gridDim.x * 256;                 // multiple of 128
    float s = 0.f, q = 0.f;
    for (int i = i0; i < NN * HCC; i += stride) {
        float v = embed[idx[i >> 7] * HCC + (i & 127)];
        x[i] = v; s += v; q += v * v;
    }
    __shared__ float ssum[256], ssq[256];
    ssum[threadIdx.x] = s; ssq[threadIdx.x] = q;
    __syncthreads();
    if (threadIdx.x < HCC) {
        atomicAdd(&stats[threadIdx.x],       ssum[threadIdx.x] + ssum[threadIdx.x + HCC]);
        atomicAdd(&stats[HCC + threadIdx.x], ssq[threadIdx.x]  + ssq[threadIdx.x + HCC]);
    }
}

// ------------------------------------------------------------ CSR build: degree
__global__ __launch_bounds__(256) void k_hist(const int* __restrict__ ei,
                                              int* __restrict__ deg) {
    int e = blockIdx.x * 256 + threadIdx.x;
    if (e >= NE) return;
    atomicAdd(&deg[ei[NE + e]], 1);
}

// chunked single-block exclusive scan: each thread serially scans its chunk
__global__ __launch_bounds__(1024) void k_scan(const int* __restrict__ deg,
                                               int* __restrict__ rowptr) {
    __shared__ int sh[1024];
    int tid = threadIdx.x;
    const int CH = (NN + 1023) / 1024;            // 49
    int st = tid * CH, en = min(st + CH, NN);
    int sum = 0;
    for (int i = st; i < en; i++) sum += deg[i];
    sh[tid] = sum;
    __syncthreads();
    for (int off = 1; off < 1024; off <<= 1) {
        int v = (tid >= off) ? sh[tid - off] : 0;
        __syncthreads();
        sh[tid] += v;
        __syncthreads();
    }
    int base = sh[tid] - sum;                     // exclusive prefix of chunk
    for (int i = st; i < en; i++) { rowptr[i] = base; base += deg[i]; }
}

// scatter edges by dst. Mutates rowptr: afterwards rowptr[d] == end(d).
__global__ __launch_bounds__(256) void k_scatter(const int* __restrict__ ei,
                                                 int* __restrict__ rowptr,
                                                 int* __restrict__ e_src) {
    int e = blockIdx.x * 256 + threadIdx.x;
    if (e >= NE) return;
    int d = ei[NE + e];
    int pos = atomicAdd(&rowptr[d], 1);
    e_src[pos] = ei[e];
}

// ---------- fused BNfin + BN-apply + Linear(128->32)+ReLU + GATw(32->128) + att
// block = 256 threads = 4 waves, 64 nodes. h written in packed bf16.
__global__ __launch_bounds__(256) void k_fused(const float* __restrict__ x,
                                               const float* __restrict__ stats,
                                               const float* __restrict__ gamma,
                                               const float* __restrict__ beta,
                                               const float* __restrict__ W1, // [32,128]
                                               const float* __restrict__ b1, // [32]
                                               const float* __restrict__ W2, // [128,32]
                                               const float* __restrict__ aS, // [4,32]
                                               const float* __restrict__ aD, // [4,32]
                                               unsigned* __restrict__ h,     // [N,64] packed
                                               float* __restrict__ asrc,     // [N,4]
                                               float* __restrict__ adst) {   // [N,4]
    __shared__ float xb[64 * XS];
    __shared__ float yt[64 * YS];
    __shared__ float w1[32 * 128];
    __shared__ float w2[128 * 32];
    __shared__ float attS[128], attD[128], ssl[256];
    int tid = threadIdx.x;
    int node0 = blockIdx.x * 64;
    int nNodes = min(64, NN - node0);

    for (int i = tid; i < 4096; i += 256) { w1[i] = W1[i]; w2[i] = W2[i]; }
    if (tid < 128) {
        attS[tid] = aS[tid]; attD[tid] = aD[tid];
        // BN finalize in-block (replaces k_bnfin)
        float mean = stats[tid] * (1.0f / NN);
        float var  = stats[HCC + tid] * (1.0f / NN) - mean * mean;
        float sc   = gamma[tid] * rsqrtf(var + BN_EPS);
        ssl[tid]       = sc;
        ssl[HCC + tid] = beta[tid] - mean * sc;
    }
    __syncthreads();   // ssl read cross-wave below

    // stage x tile with BN applied (coalesced float4 global reads)
    for (int f4 = tid; f4 < nNodes * 32; f4 += 256) {
        int f = f4 * 4; int n = f >> 7; int c = f & 127;
        float4 xv = *(const float4*)(x + (size_t)(node0 + n) * HCC + c);
        float* dst = &xb[n * XS + c];
        dst[0] = xv.x * ssl[c]     + ssl[HCC + c];
        dst[1] = xv.y * ssl[c + 1] + ssl[HCC + c + 1];
        dst[2] = xv.z * ssl[c + 2] + ssl[HCC + c + 2];
        dst[3] = xv.w * ssl[c + 3] + ssl[HCC + c + 3];
    }
    __syncthreads();

    int lane = tid & 63, wv = tid >> 6;
    int n = lane;

    // ---- stage 1: y[n][j0..j0+7]
    {
        int j0 = wv * 8;
        float acc[8];
#pragma unroll
        for (int k = 0; k < 8; k++) acc[k] = b1[j0 + k];
        if (n < nNodes) {
            for (int cb = 0; cb < 128; cb += 4) {
                float xv0 = xb[n * XS + cb],     xv1 = xb[n * XS + cb + 1];
                float xv2 = xb[n * XS + cb + 2], xv3 = xb[n * XS + cb + 3];
#pragma unroll
                for (int k = 0; k < 8; k++) {
                    float4 w = *(const float4*)&w1[(j0 + k) * 128 + cb];
                    acc[k] += xv0 * w.x + xv1 * w.y + xv2 * w.z + xv3 * w.w;
                }
            }
#pragma unroll
            for (int k = 0; k < 8; k++) yt[n * YS + j0 + k] = fmaxf(acc[k], 0.f);
        }
    }
    __syncthreads();

    // ---- stage 2: h[n][k0..k0+31] (bf16), head hd = wv, + attention dots
    if (n < nNodes) {
        int k0 = wv * 32, hd = wv;
        float yreg[32];
#pragma unroll
        for (int j = 0; j < 32; j++) yreg[j] = yt[n * YS + j];
        float sa = 0.f, da = 0.f;
        unsigned* hrow = h + (size_t)(node0 + n) * 64;   // 64 uints per node
        for (int kb = 0; kb < 32; kb += 8) {
            float acck[8];
#pragma unroll
            for (int kk = 0; kk < 8; kk++) acck[kk] = 0.f;
#pragma unroll
            for (int j = 0; j < 32; j += 4) {
#pragma unroll
                for (int kk = 0; kk < 8; kk++) {
                    float4 w = *(const float4*)&w2[(k0 + kb + kk) * 32 + j];
                    acck[kk] += yreg[j] * w.x + yreg[j + 1] * w.y +
                                yreg[j + 2] * w.z + yreg[j + 3] * w.w;
                }
            }
#pragma unroll
            for (int kk = 0; kk < 8; kk++) {
                sa += acck[kk] * attS[hd * 32 + kb + kk];
                da += acck[kk] * attD[hd * 32 + kb + kk];
            }
            uint4 pk;
            pk.x = f2bf_pack(acck[0], acck[1]);
            pk.y = f2bf_pack(acck[2], acck[3]);
            pk.z = f2bf_pack(acck[4], acck[5]);
            pk.w = f2bf_pack(acck[6], acck[7]);
            *(uint4*)(hrow + ((k0 + kb) >> 1)) = pk;
        }
        asrc[(node0 + n) * 4 + hd] = sa;
        adst[(node0 + n) * 4 + hd] = da;
    }
}

// -------- gather-aggregate: wave per 4 nodes, lane = 2 channels (1 packed uint).
// Optionally accumulates BN stats of the produced x for the next layer.
__global__ __launch_bounds__(256) void k_agg(const int* __restrict__ rowptr,
                                             const int* __restrict__ e_src,
                                             const float* __restrict__ asrc,
                                             const float* __restrict__ adst,
                                             const unsigned* __restrict__ h, // [N,64]
                                             const float* __restrict__ gat_b,
                                             float* __restrict__ xo,
                                             float* __restrict__ stats,
                                             int do_stats) {
    int tid = threadIdx.x, lane = tid & 63, wv = tid >> 6;
    int c0 = lane * 2, hd = lane >> 4;
    int nodeBase = blockIdx.x * 16 + wv * 4;
    float bs0 = gat_b[c0], bs1 = gat_b[c0 + 1];
    float S0 = 0, S1 = 0, Q0 = 0, Q1 = 0;
    for (int nn = 0; nn < 4; nn++) {
        int d = nodeBase + nn;
        if (d >= NN) break;
        float adv = adst[d * 4 + hd];
        float sl = asrc[d * 4 + hd] + adv; sl = sl > 0.f ? sl : 0.2f * sl;
        float w = __expf(sl);
        unsigned hp = h[(size_t)d * 64 + lane];
        float a0 = w * bf_lo(hp), a1 = w * bf_hi(hp), ws = w;
        int begin = d ? rowptr[d - 1] : 0, end = rowptr[d];
        int j = begin;
        for (; j + 4 <= end; j += 4) {
            int sA = e_src[j], sB = e_src[j + 1], sC = e_src[j + 2], sD = e_src[j + 3];
            float lA = asrc[sA * 4 + hd] + adv;
            float lB = asrc[sB * 4 + hd] + adv;
            float lC = asrc[sC * 4 + hd] + adv;
            float lD = asrc[sD * 4 + hd] + adv;
            unsigned pA = h[(size_t)sA * 64 + lane];
            unsigned pB = h[(size_t)sB * 64 + lane];
            unsigned pC = h[(size_t)sC * 64 + lane];
            unsigned pD = h[(size_t)sD * 64 + lane];
            lA = lA > 0.f ? lA : 0.2f * lA;  lB = lB > 0.f ? lB : 0.2f * lB;
            lC = lC > 0.f ? lC : 0.2f * lC;  lD = lD > 0.f ? lD : 0.2f * lD;
            float wA = __expf(lA), wB = __expf(lB), wC = __expf(lC), wD = __expf(lD);
            a0 += wA * bf_lo(pA) + wB * bf_lo(pB) + wC * bf_lo(pC) + wD * bf_lo(pD);
            a1 += wA * bf_hi(pA) + wB * bf_hi(pB) + wC * bf_hi(pC) + wD * bf_hi(pD);
            ws += wA + wB + wC + wD;
        }
        for (; j < end; j++) {
            int s = e_src[j];
            float l = asrc[s * 4 + hd] + adv; l = l > 0.f ? l : 0.2f * l;
            float we = __expf(l);
            unsigned p = h[(size_t)s * 64 + lane];
            a0 += we * bf_lo(p); a1 += we * bf_hi(p); ws += we;
        }
        float inv = 1.0f / (ws + 1e-16f);
        float o0 = a0 * inv + bs0, o1 = a1 * inv + bs1;
        *(float2*)(xo + (size_t)d * HCC + c0) = make_float2(o0, o1);
        S0 += o0; S1 += o1; Q0 += o0 * o0; Q1 += o1 * o1;
    }
    if (!do_stats) return;
    __shared__ float redS[512], redQ[512];
    redS[wv * 128 + c0] = S0; redS[wv * 128 + c0 + 1] = S1;
    redQ[wv * 128 + c0] = Q0; redQ[wv * 128 + c0 + 1] = Q1;
    __syncthreads();
    if (tid < 128) {
        float v = redS[tid] + redS[128 + tid] + redS[256 + tid] + redS[384 + tid];
        atomicAdd(&stats[tid], v);
    } else if (tid < 256) {
        int c = tid - 128;
        float v = redQ[c] + redQ[128 + c] + redQ[256 + c] + redQ[384 + c];
        atomicAdd(&stats[128 + c], v);
    }
}

// ------------------------------------------------------- readout + graph pool
__global__ __launch_bounds__(256) void k_readout(const float* __restrict__ x,
                                                 const int* __restrict__ batch,
                                                 const float* __restrict__ W,  // [10,128]
                                                 const float* __restrict__ bb, // [10]
                                                 float* __restrict__ out) {    // [128,10]
    int i = blockIdx.x * 256 + threadIdx.x;
    if (i >= NN * NOUT) return;
    int n = i / NOUT, j = i - n * NOUT;
    const float* xr = x + (size_t)n * HCC;
    const float* wr = W + j * HCC;
    float acc = bb[j];
#pragma unroll
    for (int c = 0; c < HCC; c += 4) {
        float4 xv = *(const float4*)(xr + c);
        float4 wv = *(const float4*)(wr + c);
        acc += xv.x * wv.x + xv.y * wv.y + xv.z * wv.z + xv.w * wv.w;
    }
    atomicAdd(&out[batch[n] * NOUT + j], acc);
}

extern "C" void kernel_launch(void* const* d_in, const int* in_sizes, int n_in,
                              void* d_out, int out_size, void* d_ws, size_t ws_size,
                              hipStream_t stream) {
    const int*   x_idx = (const int*)d_in[0];
    const int*   ei    = (const int*)d_in[1];
    const int*   batch = (const int*)d_in[2];
    const float* embed = (const float*)d_in[3];
    const float* bn_g  = (const float*)d_in[4];
    const float* bn_b  = (const float*)d_in[5];
    const float* lin_W = (const float*)d_in[6];
    const float* lin_b = (const float*)d_in[7];
    const float* gat_W = (const float*)d_in[8];
    const float* att_s = (const float*)d_in[9];
    const float* att_d = (const float*)d_in[10];
    const float* gat_b = (const float*)d_in[11];
    const float* ro_W  = (const float*)d_in[12];
    const float* ro_b  = (const float*)d_in[13];
    float* out = (float*)d_out;

    // workspace layout
    float*    x     = (float*)d_ws;                 // [N,128] fp32
    unsigned* h     = (unsigned*)(x + (size_t)NN * HCC);   // [N,64] packed bf16
    float*    asrc  = (float*)(h + (size_t)NN * 64);       // [N,4]
    float*    adst  = asrc + (size_t)NN * NHD;      // [N,4]
    float*    stats = adst + (size_t)NN * NHD;      // [4][256] per-layer sum,sumsq
    int*      deg    = (int*)(stats + 4 * 2 * HCC); // [N]
    int*      rowptr = deg + NN;                    // [N]
    int*      e_src  = rowptr + NN;                 // [E]

    hipMemsetAsync(stats, 0, 4 * 2 * HCC * sizeof(float), stream);
    hipMemsetAsync(deg, 0, NN * sizeof(int), stream);

    k_embed_stats<<<512, 256, 0, stream>>>(x_idx, embed, x, stats);

    // CSR build (graph is static across layers)
    k_hist<<<(NE + 255) / 256, 256, 0, stream>>>(ei, deg);
    k_scan<<<1, 1024, 0, stream>>>(deg, rowptr);
    k_scatter<<<(NE + 255) / 256, 256, 0, stream>>>(ei, rowptr, e_src);

    for (int l = 0; l < NL; ++l) {
        k_fused<<<(NN + 63) / 64, 256, 0, stream>>>(x, stats + l * 2 * HCC,
                                                    bn_g + l * HCC, bn_b + l * HCC,
                                                    lin_W + l * CC * HCC, lin_b + l * CC,
                                                    gat_W + l * HCC * CC,
                                                    att_s + l * NHD * CC,
                                                    att_d + l * NHD * CC,
                                                    h, asrc, adst);
        k_agg<<<(NN + 15) / 16, 256, 0, stream>>>(rowptr, e_src, asrc, adst, h,
                                                  gat_b + l * HCC, x,
                                                  stats + (l + 1) * 2 * HCC,
                                                  (l < NL - 1) ? 1 : 0);
    }

    hipMemsetAsync(out, 0, NG * NOUT * sizeof(float), stream);
    k_readout<<<(NN * NOUT + 255) / 256, 256, 0, stream>>>(x, batch, ro_W, ro_b, out);
}